// Round 6
// baseline (492.624 us; speedup 1.0000x reference)
//
#include <hip/hip_runtime.h>
#include <hip/hip_bf16.h>

// Problem constants
#define BSZ      2
#define LTOK     21760            // 128*128 + 64*64 + 32*32 + 16*16
#define NTOK     (BSZ * LTOK)     // 43520 = 128 * 340
#define DMODEL   256
#define DFFN     1024

typedef __attribute__((ext_vector_type(8))) short short8;   // 8 bf16 = 4 VGPRs
typedef __attribute__((ext_vector_type(4))) float f32x4;

__device__ __forceinline__ unsigned short f2bf(float x) {
    __hip_bfloat16 h = __float2bfloat16(x);
    return *reinterpret_cast<unsigned short*>(&h);
}
__device__ __forceinline__ float bf2f(unsigned short u) {
    union { unsigned int i; float f; } c; c.i = ((unsigned int)u) << 16; return c.f;
}
__device__ __forceinline__ float bflo(unsigned int u) {
    union { unsigned int i; float f; } c; c.i = u << 16; return c.f;
}
__device__ __forceinline__ float bfhi(unsigned int u) {
    union { unsigned int i; float f; } c; c.i = u & 0xffff0000u; return c.f;
}

// async global->LDS, 16B per lane; LDS dest = wave-uniform base + lane*16B
__device__ __forceinline__ void gload_lds16(const void* g, void* l) {
    __builtin_amdgcn_global_load_lds(
        (const __attribute__((address_space(1))) unsigned int*)g,
        (__attribute__((address_space(3))) unsigned int*)l, 16, 0, 0);
}

#define TM 128
#define TN 256
#define TBK 32
#define BUFSZ (TM * TBK + TN * TBK)   // 12288 ushorts = 24 KB per buffer
#define EBS 264   // epilogue LDS row stride in ushorts (528 B, 16B-aligned)

// ---------------------------------------------------------------------------
// GEMM core (verified R5 structure): double-buffered global_load_lds staging.
// 128x256 tile, BK=32, 4 waves 2x2, wave = 4x8 MFMA 16x16x32.
// ---------------------------------------------------------------------------
__device__ __forceinline__ void stage_tile(
    const unsigned short* aR0, const unsigned short* aR1,
    const unsigned short* bR0, const unsigned short* bR1,
    const unsigned short* bR2, const unsigned short* bR3,
    int k0, unsigned short* sA, unsigned short* sB, int sr)
{
    gload_lds16(aR0 + k0, &sA[(sr + 0)  * 512]);
    gload_lds16(aR1 + k0, &sA[(sr + 4)  * 512]);
    gload_lds16(bR0 + k0, &sB[(sr + 0)  * 512]);
    gload_lds16(bR1 + k0, &sB[(sr + 4)  * 512]);
    gload_lds16(bR2 + k0, &sB[(sr + 8)  * 512]);
    gload_lds16(bR3 + k0, &sB[(sr + 12) * 512]);
}

__device__ __forceinline__ void compute_tile(
    const unsigned short* sA, const unsigned short* sB,
    int lane, int wm, int wn, f32x4 acc[4][8])
{
    short8 af[4], bfr[8];
    #pragma unroll
    for (int i = 0; i < 4; ++i)
        af[i] = *(const short8*)&sA[(wm * 4 + i) * 512 + lane * 8];
    #pragma unroll
    for (int j = 0; j < 8; ++j)
        bfr[j] = *(const short8*)&sB[(wn * 8 + j) * 512 + lane * 8];
    #pragma unroll
    for (int i = 0; i < 4; ++i)
        #pragma unroll
        for (int j = 0; j < 8; ++j)
            acc[i][j] = __builtin_amdgcn_mfma_f32_16x16x32_bf16(
                af[i], bfr[j], acc[i][j], 0, 0, 0);
}

__device__ __forceinline__ void gemm_core(
    const unsigned short* __restrict__ A,
    const unsigned short* __restrict__ Bt,
    unsigned short* smem,
    int bm, int bn, int N, int K,
    int tid, int lane, int wm, int wn,
    f32x4 acc[4][8])
{
    const int sr = tid >> 6;
    const int fr = lane & 15;
    const int fk = (lane >> 4) * 8;

    const unsigned short* aR0 = A + (size_t)(bm + (sr + 0) * 16 + fr) * K + fk;
    const unsigned short* aR1 = A + (size_t)(bm + (sr + 4) * 16 + fr) * K + fk;
    const unsigned short* bR0 = Bt + (size_t)min(bn + (sr + 0)  * 16 + fr, N - 1) * K + fk;
    const unsigned short* bR1 = Bt + (size_t)min(bn + (sr + 4)  * 16 + fr, N - 1) * K + fk;
    const unsigned short* bR2 = Bt + (size_t)min(bn + (sr + 8)  * 16 + fr, N - 1) * K + fk;
    const unsigned short* bR3 = Bt + (size_t)min(bn + (sr + 12) * 16 + fr, N - 1) * K + fk;

    unsigned short* sA0 = smem;
    unsigned short* sB0 = smem + TM * TBK;
    unsigned short* sA1 = smem + BUFSZ;
    unsigned short* sB1 = smem + BUFSZ + TM * TBK;

    stage_tile(aR0, aR1, bR0, bR1, bR2, bR3, 0, sA0, sB0, sr);
    __syncthreads();

    for (int k0 = 0; k0 < K; k0 += 2 * TBK) {
        if (k0 + TBK < K)
            stage_tile(aR0, aR1, bR0, bR1, bR2, bR3, k0 + TBK, sA1, sB1, sr);
        compute_tile(sA0, sB0, lane, wm, wn, acc);
        __syncthreads();
        if (k0 + 2 * TBK < K)
            stage_tile(aR0, aR1, bR0, bR1, bR2, bR3, k0 + 2 * TBK, sA0, sB0, sr);
        compute_tile(sA1, sB1, lane, wm, wn, acc);
        __syncthreads();
    }
}

// ---------------------------------------------------------------------------
// Fused projection dispatch: bx=0 -> value (masked, head-major vT out);
// bx=1,2 -> qproj (N=384, row-major out). One launch, 3*(NTOK/TM) blocks.
// ---------------------------------------------------------------------------
__global__ __launch_bounds__(256, 2) void gemm_proj(
    const unsigned short* __restrict__ A0, const unsigned short* __restrict__ B0,
    const float* __restrict__ bias0, unsigned short* __restrict__ C0,
    const unsigned char* __restrict__ mask,
    const unsigned short* __restrict__ A1, const unsigned short* __restrict__ B1,
    const float* __restrict__ bias1, unsigned short* __restrict__ C1)
{
    __shared__ __align__(16) unsigned short smem[2 * BUFSZ];
    const int tid  = threadIdx.x;
    const int lane = tid & 63;
    const int wave = tid >> 6;
    const int wm = wave >> 1, wn = wave & 1;
    const int bm = blockIdx.y * TM;
    const int bx = blockIdx.x;

    const int isv = (bx == 0);
    const unsigned short* A    = isv ? A0 : A1;
    const unsigned short* Bt   = isv ? B0 : B1;
    const float*          bias = isv ? bias0 : bias1;
    const int N  = isv ? 256 : 384;
    const int bn = isv ? 0 : (bx - 1) * 256;
    const int K  = 256;

    f32x4 acc[4][8];
    #pragma unroll
    for (int i = 0; i < 4; ++i)
        #pragma unroll
        for (int j = 0; j < 8; ++j)
            acc[i][j] = (f32x4){0.f, 0.f, 0.f, 0.f};

    gemm_core(A, Bt, smem, bm, bn, N, K, tid, lane, wm, wn, acc);

    const int r0 = (lane >> 4) * 4;
    const int c0 = lane & 15;
    unsigned short* eb = smem;
    #pragma unroll
    for (int i = 0; i < 4; ++i) {
        if (i) __syncthreads();
        #pragma unroll
        for (int j = 0; j < 8; ++j) {
            const int col = bn + wn * 128 + j * 16 + c0;
            const float bj = (col < N) ? bias[col] : 0.f;
            #pragma unroll
            for (int r = 0; r < 4; ++r) {
                const int row = bm + wm * 64 + i * 16 + r0 + r;
                float v = acc[i][j][r] + bj;
                if (isv && mask[row]) v = 0.f;
                eb[(wm * 16 + r0 + r) * EBS + wn * 128 + j * 16 + c0] = f2bf(v);
            }
        }
        __syncthreads();
        #pragma unroll
        for (int qq = 0; qq < 4; ++qq) {
            const int q  = tid + qq * 256;
            const int rl = q >> 5;
            const int ch = q & 31;
            const int grow = bm + (rl >> 4) * 64 + i * 16 + (rl & 15);
            const int colb = bn + ch * 8;
            if (colb < N) {
                const uint4 val = *(const uint4*)&eb[rl * EBS + ch * 8];
                if (isv) {
                    const int bb   = grow >= LTOK;
                    const int srow = grow - bb * LTOK;
                    const int hcol = ch >> 2;
                    const int d    = (ch & 3) * 8;
                    *(uint4*)&C0[((size_t)(bb * 8 + hcol) * LTOK + srow) * 32 + d] = val;
                } else {
                    *(uint4*)&C1[(size_t)grow * 384 + colb] = val;
                }
            }
        }
    }
}

// ---------------------------------------------------------------------------
// GEMM + LayerNorm fusion (N=256):  y = LN(resid + A@Bt^T + bias) * g + be
// (used for LN1; bf16 out)
// ---------------------------------------------------------------------------
__global__ __launch_bounds__(256, 2) void gemm_ln(
    const unsigned short* __restrict__ A,
    const unsigned short* __restrict__ Bt, const float* __restrict__ bias,
    const unsigned short* __restrict__ resid,
    const float* __restrict__ g, const float* __restrict__ be,
    float* __restrict__ outF, unsigned short* __restrict__ outB, int K)
{
    __shared__ __align__(16) unsigned short smem[2 * BUFSZ];
    const int tid  = threadIdx.x;
    const int lane = tid & 63;
    const int wave = tid >> 6;
    const int wm = wave >> 1, wn = wave & 1;
    const int bm = blockIdx.y * TM;

    f32x4 acc[4][8];
    #pragma unroll
    for (int i = 0; i < 4; ++i)
        #pragma unroll
        for (int j = 0; j < 8; ++j)
            acc[i][j] = (f32x4){0.f, 0.f, 0.f, 0.f};

    gemm_core(A, Bt, smem, bm, 0, 256, K, tid, lane, wm, wn, acc);

    const int r0 = (lane >> 4) * 4;
    const int c0 = lane & 15;
    unsigned short* eb = smem;

    #pragma unroll
    for (int i = 0; i < 4; ++i) {
        if (i) __syncthreads();
        #pragma unroll
        for (int j = 0; j < 8; ++j) {
            const int col = wn * 128 + j * 16 + c0;
            const float bj = bias[col];
            #pragma unroll
            for (int r = 0; r < 4; ++r)
                eb[(wm * 16 + r0 + r) * EBS + col] = f2bf(acc[i][j][r] + bj);
        }
        __syncthreads();

        const int row = tid >> 3;            // 0..31
        const int l   = tid & 7;             // lane within row
        const int grow = bm + (row >> 4) * 64 + i * 16 + (row & 15);
        const unsigned short* rr = resid + (size_t)grow * 256 + l * 32;

        float s = 0.f, sq = 0.f;
        #pragma unroll
        for (int k = 0; k < 4; ++k) {
            const uint4 e = *(const uint4*)&eb[row * EBS + l * 32 + k * 8];
            const uint4 rv = *(const uint4*)(rr + k * 8);
            const unsigned int eu[4] = {e.x, e.y, e.z, e.w};
            const unsigned int ru[4] = {rv.x, rv.y, rv.z, rv.w};
            #pragma unroll
            for (int q = 0; q < 4; ++q) {
                const float v0 = bflo(eu[q]) + bflo(ru[q]);
                const float v1 = bfhi(eu[q]) + bfhi(ru[q]);
                s += v0 + v1;
                sq += v0 * v0 + v1 * v1;
            }
        }
        #pragma unroll
        for (int m = 4; m; m >>= 1) {
            s  += __shfl_xor(s, m, 8);
            sq += __shfl_xor(sq, m, 8);
        }
        const float mean = s * (1.f / 256.f);
        const float var  = sq * (1.f / 256.f) - mean * mean;
        const float rs   = rsqrtf(var + 1e-5f);

        #pragma unroll
        for (int k = 0; k < 4; ++k) {
            const int col = l * 32 + k * 8;
            const uint4 e = *(const uint4*)&eb[row * EBS + col];
            const uint4 rv = *(const uint4*)(rr + k * 8);
            const unsigned int eu[4] = {e.x, e.y, e.z, e.w};
            const unsigned int ru[4] = {rv.x, rv.y, rv.z, rv.w};
            float o[8];
            #pragma unroll
            for (int q = 0; q < 4; ++q) {
                const float g0 = g[col + q * 2],     b0 = be[col + q * 2];
                const float g1 = g[col + q * 2 + 1], b1 = be[col + q * 2 + 1];
                o[q * 2]     = (bflo(eu[q]) + bflo(ru[q]) - mean) * rs * g0 + b0;
                o[q * 2 + 1] = (bfhi(eu[q]) + bfhi(ru[q]) - mean) * rs * g1 + b1;
            }
            if (outB) {
                uint4 pk;
                pk.x = (unsigned)f2bf(o[0]) | ((unsigned)f2bf(o[1]) << 16);
                pk.y = (unsigned)f2bf(o[2]) | ((unsigned)f2bf(o[3]) << 16);
                pk.z = (unsigned)f2bf(o[4]) | ((unsigned)f2bf(o[5]) << 16);
                pk.w = (unsigned)f2bf(o[6]) | ((unsigned)f2bf(o[7]) << 16);
                *(uint4*)(outB + (size_t)grow * 256 + col) = pk;
            } else {
                float4 f0 = make_float4(o[0], o[1], o[2], o[3]);
                float4 f1 = make_float4(o[4], o[5], o[6], o[7]);
                *(float4*)(outF + (size_t)grow * 256 + col) = f0;
                *(float4*)(outF + (size_t)grow * 256 + col + 4) = f1;
            }
        }
        __syncthreads();
    }
}

// ---------------------------------------------------------------------------
// Fused FFN:  out = LN2(xb + relu(xb@w1 + b1)@w2 + b2)
// Block = 64 tokens, 4 waves 2x2.  xb rows staged ONCE in LDS (A-layout);
// 8 hid-chunks of 128: ffn1 chunk-GEMM (K=256) -> relu -> hid chunk in LDS
// (A-layout) -> ffn2 partial (K=128) accumulated in registers.  hidb never
// touches global memory (saves ~245 MB/iter round-trip vs split kernels).
// LDS: sxb 32KB + hidA 16KB + 2x8KB+2x8KB staging = 80KB -> 2 blocks/CU.
// ---------------------------------------------------------------------------
#define FTM 64

__device__ __forceinline__ void ffn_f1(
    const unsigned short* sxb, const unsigned short* buf, int ks,
    int lane, int wm, int wn, f32x4 acc1[2][4])
{
    short8 af[2], bfr[4];
    #pragma unroll
    for (int i = 0; i < 2; ++i)
        af[i] = *(const short8*)&sxb[ks * 2048 + (wm * 2 + i) * 512 + lane * 8];
    #pragma unroll
    for (int j = 0; j < 4; ++j)
        bfr[j] = *(const short8*)&buf[(wn * 4 + j) * 512 + lane * 8];
    #pragma unroll
    for (int i = 0; i < 2; ++i)
        #pragma unroll
        for (int j = 0; j < 4; ++j)
            acc1[i][j] = __builtin_amdgcn_mfma_f32_16x16x32_bf16(
                af[i], bfr[j], acc1[i][j], 0, 0, 0);
}

__device__ __forceinline__ void ffn_f2(
    const unsigned short* hidA, const unsigned short* buf, int ks,
    int lane, int wm, int wn, f32x4 acc2[2][8])
{
    short8 af[2], bfr[8];
    #pragma unroll
    for (int i = 0; i < 2; ++i)
        af[i] = *(const short8*)&hidA[ks * 2048 + (wm * 2 + i) * 512 + lane * 8];
    #pragma unroll
    for (int j = 0; j < 8; ++j)
        bfr[j] = *(const short8*)&buf[(wn * 8 + j) * 512 + lane * 8];
    #pragma unroll
    for (int i = 0; i < 2; ++i)
        #pragma unroll
        for (int j = 0; j < 8; ++j)
            acc2[i][j] = __builtin_amdgcn_mfma_f32_16x16x32_bf16(
                af[i], bfr[j], acc2[i][j], 0, 0, 0);
}

__global__ __launch_bounds__(256, 2) void ffn_fused(
    const unsigned short* __restrict__ xb,   // [NTOK][256]
    const unsigned short* __restrict__ w1T,  // [1024][256]
    const float* __restrict__ b1,
    const unsigned short* __restrict__ w2T,  // [256][1024]
    const float* __restrict__ b2,
    const float* __restrict__ g, const float* __restrict__ be,
    float* __restrict__ outF)
{
    __shared__ __align__(16) unsigned short smem[40960];   // 80 KB
    unsigned short* sxb  = smem;            // [8 kc][2048]  (xb A-layout)
    unsigned short* hidA = smem + 16384;    // [4 kc][2048]  (hid chunk A-layout)
    unsigned short* bs0  = smem + 24576;    // staging buf 0 (8192)
    unsigned short* bs1  = smem + 32768;    // staging buf 1 (8192)

    const int tid  = threadIdx.x;
    const int lane = tid & 63;
    const int wave = tid >> 6;
    const int wm = wave >> 1, wn = wave & 1;
    const int bm = blockIdx.x * FTM;
    const int fr = lane & 15;
    const int fk = (lane >> 4) * 8;
    const int sr = wave;                    // staging stripe

    // per-thread global bases (k-invariant)
    const unsigned short* xrow = xb + (size_t)(bm + sr * 16 + fr) * 256 + fk;
    const unsigned short* w1b0 = w1T + (size_t)((sr + 0) * 16 + fr) * 256 + fk;
    const unsigned short* w1b1 = w1T + (size_t)((sr + 4) * 16 + fr) * 256 + fk;
    const unsigned short* w2b0 = w2T + (size_t)((sr + 0)  * 16 + fr) * 1024 + fk;
    const unsigned short* w2b1 = w2T + (size_t)((sr + 4)  * 16 + fr) * 1024 + fk;
    const unsigned short* w2b2 = w2T + (size_t)((sr + 8)  * 16 + fr) * 1024 + fk;
    const unsigned short* w2b3 = w2T + (size_t)((sr + 12) * 16 + fr) * 1024 + fk;

    f32x4 acc2[2][8];
    #pragma unroll
    for (int i = 0; i < 2; ++i)
        #pragma unroll
        for (int j = 0; j < 8; ++j)
            acc2[i][j] = (f32x4){0.f, 0.f, 0.f, 0.f};

    const int r0 = (lane >> 4) * 4;
    const int c0 = lane & 15;

    // ---- prologue: stage xb (all 8 k-chunks) + B1 chunk0 ks0 ----
    #pragma unroll
    for (int kc = 0; kc < 8; ++kc)
        gload_lds16(xrow + kc * 32, &sxb[kc * 2048 + sr * 512]);
    gload_lds16(w1b0, &bs0[(sr + 0) * 512]);
    gload_lds16(w1b1, &bs0[(sr + 4) * 512]);
    __syncthreads();

    #define STG_B1(c_, ks_, buf_)                                            \
        gload_lds16(w1b0 + (c_) * 32768 + (ks_) * 32, &buf_[(sr + 0) * 512]);\
        gload_lds16(w1b1 + (c_) * 32768 + (ks_) * 32, &buf_[(sr + 4) * 512]);
    #define STG_B2(c_, ks_, buf_)                                            \
        gload_lds16(w2b0 + (c_) * 128 + (ks_) * 32, &buf_[(sr + 0)  * 512]); \
        gload_lds16(w2b1 + (c_) * 128 + (ks_) * 32, &buf_[(sr + 4)  * 512]); \
        gload_lds16(w2b2 + (c_) * 128 + (ks_) * 32, &buf_[(sr + 8)  * 512]); \
        gload_lds16(w2b3 + (c_) * 128 + (ks_) * 32, &buf_[(sr + 12) * 512]);

    for (int c = 0; c < 8; ++c) {
        f32x4 acc1[2][4];
        #pragma unroll
        for (int i = 0; i < 2; ++i)
            #pragma unroll
            for (int j = 0; j < 4; ++j)
                acc1[i][j] = (f32x4){0.f, 0.f, 0.f, 0.f};

        // ---- ffn1: 8 k-steps, double-buffered ----
        STG_B1(c, 1, bs1); ffn_f1(sxb, bs0, 0, lane, wm, wn, acc1); __syncthreads();
        STG_B1(c, 2, bs0); ffn_f1(sxb, bs1, 1, lane, wm, wn, acc1); __syncthreads();
        STG_B1(c, 3, bs1); ffn_f1(sxb, bs0, 2, lane, wm, wn, acc1); __syncthreads();
        STG_B1(c, 4, bs0); ffn_f1(sxb, bs1, 3, lane, wm, wn, acc1); __syncthreads();
        STG_B1(c, 5, bs1); ffn_f1(sxb, bs0, 4, lane, wm, wn, acc1); __syncthreads();
        STG_B1(c, 6, bs0); ffn_f1(sxb, bs1, 5, lane, wm, wn, acc1); __syncthreads();
        STG_B1(c, 7, bs1); ffn_f1(sxb, bs0, 6, lane, wm, wn, acc1); __syncthreads();
        STG_B2(c, 0, bs0); ffn_f1(sxb, bs1, 7, lane, wm, wn, acc1); __syncthreads();

        // ---- bias + relu -> hidA (A-staged layout) ----
        #pragma unroll
        for (int j = 0; j < 4; ++j) {
            const int colj = wn * 64 + j * 16 + c0;
            const float bj = b1[c * 128 + colj];
            const int kc2  = colj >> 5;
            const int sel  = (colj >> 3) & 3;
            const int c7   = colj & 7;
            #pragma unroll
            for (int i = 0; i < 2; ++i) {
                const int base = kc2 * 2048 + (wm * 2 + i) * 512
                               + (r0 | (sel << 4)) * 8 + c7;
                #pragma unroll
                for (int r = 0; r < 4; ++r)
                    hidA[base + r * 8] = f2bf(fmaxf(acc1[i][j][r] + bj, 0.f));
            }
        }
        __syncthreads();   // hidA visible + B2 ks0 vmcnt drained

        // ---- ffn2 partial: 4 k-steps, double-buffered ----
        STG_B2(c, 1, bs1); ffn_f2(hidA, bs0, 0, lane, wm, wn, acc2); __syncthreads();
        STG_B2(c, 2, bs0); ffn_f2(hidA, bs1, 1, lane, wm, wn, acc2); __syncthreads();
        STG_B2(c, 3, bs1); ffn_f2(hidA, bs0, 2, lane, wm, wn, acc2); __syncthreads();
        if (c < 7) { STG_B1(c + 1, 0, bs0); }
        ffn_f2(hidA, bs1, 3, lane, wm, wn, acc2); __syncthreads();
    }
    #undef STG_B1
    #undef STG_B2

    // ---- epilogue: LN2 over 2 slabs of 32 rows (proven gemm_ln pattern) ----
    unsigned short* eb = smem;   // sxb region dead
    #pragma unroll
    for (int i = 0; i < 2; ++i) {
        if (i) __syncthreads();
        #pragma unroll
        for (int j = 0; j < 8; ++j) {
            const int col = wn * 128 + j * 16 + c0;
            const float bj = b2[col];
            #pragma unroll
            for (int r = 0; r < 4; ++r)
                eb[(wm * 16 + r0 + r) * EBS + col] = f2bf(acc2[i][j][r] + bj);
        }
        __syncthreads();

        const int row = tid >> 3;            // 0..31
        const int l   = tid & 7;
        const int grow = bm + (row >> 4) * 32 + i * 16 + (row & 15);
        const unsigned short* rr = xb + (size_t)grow * 256 + l * 32;

        float s = 0.f, sq = 0.f;
        #pragma unroll
        for (int k = 0; k < 4; ++k) {
            const uint4 e = *(const uint4*)&eb[row * EBS + l * 32 + k * 8];
            const uint4 rv = *(const uint4*)(rr + k * 8);
            const unsigned int eu[4] = {e.x, e.y, e.z, e.w};
            const unsigned int ru[4] = {rv.x, rv.y, rv.z, rv.w};
            #pragma unroll
            for (int q = 0; q < 4; ++q) {
                const float v0 = bflo(eu[q]) + bflo(ru[q]);
                const float v1 = bfhi(eu[q]) + bfhi(ru[q]);
                s += v0 + v1;
                sq += v0 * v0 + v1 * v1;
            }
        }
        #pragma unroll
        for (int m = 4; m; m >>= 1) {
            s  += __shfl_xor(s, m, 8);
            sq += __shfl_xor(sq, m, 8);
        }
        const float mean = s * (1.f / 256.f);
        const float var  = sq * (1.f / 256.f) - mean * mean;
        const float rs   = rsqrtf(var + 1e-5f);

        #pragma unroll
        for (int k = 0; k < 4; ++k) {
            const int col = l * 32 + k * 8;
            const uint4 e = *(const uint4*)&eb[row * EBS + col];
            const uint4 rv = *(const uint4*)(rr + k * 8);
            const unsigned int eu[4] = {e.x, e.y, e.z, e.w};
            const unsigned int ru[4] = {rv.x, rv.y, rv.z, rv.w};
            float o[8];
            #pragma unroll
            for (int q = 0; q < 4; ++q) {
                const float g0 = g[col + q * 2],     b0 = be[col + q * 2];
                const float g1 = g[col + q * 2 + 1], b1v = be[col + q * 2 + 1];
                o[q * 2]     = (bflo(eu[q]) + bflo(ru[q]) - mean) * rs * g0 + b0;
                o[q * 2 + 1] = (bfhi(eu[q]) + bfhi(ru[q]) - mean) * rs * g1 + b1v;
            }
            float4 f0 = make_float4(o[0], o[1], o[2], o[3]);
            float4 f1 = make_float4(o[4], o[5], o[6], o[7]);
            *(float4*)(outF + (size_t)grow * 256 + col) = f0;
            *(float4*)(outF + (size_t)grow * 256 + col + 4) = f1;
        }
        __syncthreads();
    }
}

// ---------------------------------------------------------------------------
// Prepass: sb = bf16(src), qs = bf16(src + pos). Vectorized x4.
// ---------------------------------------------------------------------------
__global__ __launch_bounds__(256) void prepass(
    const float* __restrict__ src, const float* __restrict__ pos,
    unsigned short* __restrict__ sb, unsigned short* __restrict__ qs)
{
    const size_t i = ((size_t)blockIdx.x * 256 + threadIdx.x) * 4;
    const float4 s = *(const float4*)(src + i);
    const float4 p = *(const float4*)(pos + i);
    ushort4 us, uq;
    us.x = f2bf(s.x); us.y = f2bf(s.y); us.z = f2bf(s.z); us.w = f2bf(s.w);
    uq.x = f2bf(s.x + p.x); uq.y = f2bf(s.y + p.y);
    uq.z = f2bf(s.z + p.z); uq.w = f2bf(s.w + p.w);
    *(ushort4*)(sb + i) = us;
    *(ushort4*)(qs + i) = uq;
}

// ---------------------------------------------------------------------------
// All weight transposes (f32 [K][N] -> bf16 [N][K]) + bias concat, 1 dispatch.
// ---------------------------------------------------------------------------
__global__ void transpose_all(
    const float* __restrict__ w_val, const float* __restrict__ w_off,
    const float* __restrict__ w_att, const float* __restrict__ w_out,
    const float* __restrict__ w1,    const float* __restrict__ w2,
    const float* __restrict__ b_off, const float* __restrict__ b_att,
    unsigned short* __restrict__ wvalT, unsigned short* __restrict__ woaT,
    unsigned short* __restrict__ woutT, unsigned short* __restrict__ w1T,
    unsigned short* __restrict__ w2T,   float* __restrict__ bcat)
{
    const int blk = blockIdx.x;
    const int tx = threadIdx.x, ty = threadIdx.y;   // 32 x 8
    if (blk == 736) {
        const int t = ty * 32 + tx;
        bcat[t] = (t < 256) ? b_off[t] : b_att[t - 256];
        if (t + 256 < 384) bcat[t + 256] = b_att[t];
        return;
    }
    const float* W; unsigned short* Wt; int K, N, base;
    if      (blk < 64)  { W = w_val; Wt = wvalT;           K = 256;  N = 256;  base = 0;   }
    else if (blk < 128) { W = w_off; Wt = woaT;            K = 256;  N = 256;  base = 64;  }
    else if (blk < 160) { W = w_att; Wt = woaT + 256*256;  K = 256;  N = 128;  base = 128; }
    else if (blk < 224) { W = w_out; Wt = woutT;           K = 256;  N = 256;  base = 160; }
    else if (blk < 480) { W = w1;    Wt = w1T;             K = 256;  N = 1024; base = 224; }
    else                { W = w2;    Wt = w2T;             K = 1024; N = 256;  base = 480; }
    const int local = blk - base;
    const int kb = local % (K / 32);
    const int nb = local / (K / 32);
    const int k0 = kb * 32, n0 = nb * 32;

    __shared__ float t[32][33];
    #pragma unroll
    for (int i = 0; i < 32; i += 8)
        t[ty + i][tx] = W[(size_t)(k0 + ty + i) * N + n0 + tx];
    __syncthreads();
    #pragma unroll
    for (int i = 0; i < 32; i += 8)
        Wt[(size_t)(n0 + ty + i) * K + k0 + tx] = f2bf(t[tx][ty + i]);
}

// ---------------------------------------------------------------------------
// Fused softmax + bilinear sampling (immediate-offset LDS rows; R4 lesson:
// XOR swizzle broke offset-immediate addressing and serialized gathers).
// ---------------------------------------------------------------------------
__global__ __launch_bounds__(256) void sample_kernel(
    const unsigned short* __restrict__ vT, const unsigned short* __restrict__ qp,
    const float* __restrict__ ref,
    const int* __restrict__ sshapes, const int* __restrict__ lstart,
    unsigned short* __restrict__ samp)
{
    __shared__ __align__(16) int   s_o[256][4];
    __shared__ __align__(16) float s_w[256][4];

    const int blk   = blockIdx.x;
    const int plane = blk & 15;
    const int chunk = blk >> 4;
    const int b = plane >> 3;
    const int h = plane & 7;
    const int s0 = chunk * 16;
    const int t = threadIdx.x;

    {
        const int tl = t >> 4;
        const int p  = t & 15;
        const int l  = p >> 2;
        const int pp = p & 3;
        const int H = sshapes[2 * l], W = sshapes[2 * l + 1];
        const float Wf = (float)W, Hf = (float)H;
        const size_t tok = (size_t)(b * LTOK + s0 + tl);

        const float ox = bf2f(qp[tok * 384 + h * 32 + l * 8 + pp * 2 + 0]);
        const float oy = bf2f(qp[tok * 384 + h * 32 + l * 8 + pp * 2 + 1]);
        const float rx = ref[tok * 8 + l * 2 + 0];
        const float ry = ref[tok * 8 + l * 2 + 1];

        const float x = (rx + ox / Wf) * Wf - 0.5f;
        const float y = (ry + oy / Hf) * Hf - 0.5f;
        const float x0 = floorf(x), y0 = floorf(y);
        const float dx = x - x0, dy = y - y0;
        const int x0i = (int)x0, y0i = (int)y0;
        const int s = lstart[l];

        const float a = bf2f(qp[tok * 384 + 256 + h * 16 + p]);
        float mx = a;
        #pragma unroll
        for (int m = 8; m; m >>= 1) mx = fmaxf(mx, __shfl_xor(mx, m, 16));
        const float e = __expf(a - mx);
        float ssum = e;
        #pragma unroll
        for (int m = 8; m; m >>= 1) ssum += __shfl_xor(ssum, m, 16);
        const float prob = e / ssum;

        const float cw[4] = {(1.f - dx) * (1.f - dy), dx * (1.f - dy),
                             (1.f - dx) * dy,         dx * dy};
        const int cx[4] = {x0i, x0i + 1, x0i,     x0i + 1};
        const int cy[4] = {y0i, y0i,     y0i + 1, y0i + 1};
        int4   o4;
        float4 w4;
        #pragma unroll
        for (int c = 0; c < 4; ++c) {
            const bool valid = (cx[c] >= 0) & (cx[c] < W) & (cy[c] >= 0) & (cy[c] < H);
            const int xi = min(max(cx[c], 0), W - 1);
            const int yi = min(max(cy[c], 0), H - 1);
            ((int*)&o4)[c]   = (s + yi * W + xi) * 64;
            ((float*)&w4)[c] = valid ? cw[c] * prob : 0.f;
        }
        const int r = p * 16 + tl;
        *(int4*)&s_o[r][0]   = o4;
        *(float4*)&s_w[r][0] = w4;
    }
    __syncthreads();

    const int tl = t >> 4;
    const int dp = t & 15;
    const char* vp = (const char*)(vT + (size_t)plane * LTOK * 32) + dp * 4;
    float acc0 = 0.f, acc1 = 0.f;
    #pragma unroll
    for (int p = 0; p < 16; ++p) {
        const int r = p * 16 + tl;
        const int4   o4 = *(const int4*)&s_o[r][0];
        const float4 w4 = *(const float4*)&s_w[r][0];
        const unsigned int u0 = *(const unsigned int*)(vp + o4.x);
        const unsigned int u1 = *(const unsigned int*)(vp + o4.y);
        const unsigned int u2 = *(const unsigned int*)(vp + o4.z);
        const unsigned int u3 = *(const unsigned int*)(vp + o4.w);
        acc0 = fmaf(w4.x, bflo(u0), acc0); acc1 = fmaf(w4.x, bfhi(u0), acc1);
        acc0 = fmaf(w4.y, bflo(u1), acc0); acc1 = fmaf(w4.y, bfhi(u1), acc1);
        acc0 = fmaf(w4.z, bflo(u2), acc0); acc1 = fmaf(w4.z, bfhi(u2), acc1);
        acc0 = fmaf(w4.w, bflo(u3), acc0); acc1 = fmaf(w4.w, bfhi(u3), acc1);
    }
    const unsigned int o = (unsigned)f2bf(acc0) | ((unsigned)f2bf(acc1) << 16);
    *(unsigned int*)(samp + (size_t)(b * LTOK + s0 + tl) * 256 + h * 32 + dp * 2) = o;
}

// ---------------------------------------------------------------------------
extern "C" void kernel_launch(void* const* d_in, const int* in_sizes, int n_in,
                              void* d_out, int out_size, void* d_ws, size_t ws_size,
                              hipStream_t stream)
{
    const float* src   = (const float*)d_in[0];
    const float* pos   = (const float*)d_in[1];
    const float* ref   = (const float*)d_in[2];
    const int*   sshap = (const int*)d_in[3];
    const int*   lstrt = (const int*)d_in[4];
    const unsigned char* mask = (const unsigned char*)d_in[5];
    const float* w_off = (const float*)d_in[6];
    const float* b_off = (const float*)d_in[7];
    const float* w_att = (const float*)d_in[8];
    const float* b_att = (const float*)d_in[9];
    const float* w_val = (const float*)d_in[10];
    const float* b_val = (const float*)d_in[11];
    const float* w_out = (const float*)d_in[12];
    const float* b_out = (const float*)d_in[13];
    const float* ln1g  = (const float*)d_in[14];
    const float* ln1b  = (const float*)d_in[15];
    const float* w1    = (const float*)d_in[16];
    const float* b1    = (const float*)d_in[17];
    const float* w2    = (const float*)d_in[18];
    const float* b2    = (const float*)d_in[19];
    const float* ln2g  = (const float*)d_in[20];
    const float* ln2b  = (const float*)d_in[21];
    float* out = (float*)d_out;

    // ---- workspace, time-disjoint reuse ----
    const size_t HSZ = (size_t)NTOK * 256 * 2;    // 22.28 MB
    char* w = (char*)d_ws;
    unsigned short* qs     = (unsigned short*)w;
    unsigned short* samp16 = (unsigned short*)w;
    unsigned short* qpb    = (unsigned short*)(w + HSZ);
    unsigned short* vT     = (unsigned short*)(w + HSZ * 5 / 2);
    unsigned short* sb     = (unsigned short*)(w + HSZ * 9 / 2);
    unsigned short* xb     = (unsigned short*)(w + HSZ * 11 / 2);
    char* wreg = w + HSZ * 13 / 2;
    unsigned short* wvalT  = (unsigned short*)wreg;
    unsigned short* woaT   = wvalT + 256 * 256;       // [384][256]
    unsigned short* woutT  = woaT + 384 * 256;
    unsigned short* w1T    = woutT + 256 * 256;
    unsigned short* w2T    = w1T + 1024 * 256;
    float*          bcat   = (float*)(w2T + 256 * 1024);

    const dim3 blk(256);

    // 1. prepass: sb = bf16(src), qs = bf16(src+pos)
    prepass<<<dim3(NTOK / 4), blk, 0, stream>>>(src, pos, sb, qs);

    // 2. all weight transposes + bias concat
    transpose_all<<<dim3(737), dim3(32, 8), 0, stream>>>(
        w_val, w_off, w_att, w_out, w1, w2, b_off, b_att,
        wvalT, woaT, woutT, w1T, w2T, bcat);

    // 3. fused: value -> vT (head-major, masked) + qproj -> qpb. 1020 blocks.
    gemm_proj<<<dim3(3, NTOK / TM), blk, 0, stream>>>(
        sb, wvalT, b_val, vT, mask, qs, woaT, bcat, qpb);

    // 4. softmax + bilinear sampling -> samp16 (qs dead)
    sample_kernel<<<dim3(16 * (LTOK / 16)), blk, 0, stream>>>(
        vT, qpb, ref, sshap, lstrt, samp16);

    // 5. xb = LN1(sb + samp @ w_out + b_out)  [fused gemm+LN]
    gemm_ln<<<dim3(1, NTOK / TM), blk, 0, stream>>>(
        samp16, woutT, b_out, sb, ln1g, ln1b, nullptr, xb, 256);

    // 6. out = LN2(xb + relu(xb@w1+b1)@w2 + b2)   [fully fused FFN]
    ffn_fused<<<dim3(NTOK / FTM), blk, 0, stream>>>(
        xb, w1T, b1, w2T, b2, ln2g, ln2b, out);
}

// Round 7
// 463.477 us; speedup vs baseline: 1.0629x; 1.0629x over previous
//
#include <hip/hip_runtime.h>
#include <hip/hip_bf16.h>

// Problem constants
#define BSZ      2
#define LTOK     21760            // 128*128 + 64*64 + 32*32 + 16*16
#define NTOK     (BSZ * LTOK)     // 43520 = 128 * 340
#define DMODEL   256
#define DFFN     1024

typedef __attribute__((ext_vector_type(8))) short short8;   // 8 bf16 = 4 VGPRs
typedef __attribute__((ext_vector_type(4))) float f32x4;

__device__ __forceinline__ unsigned short f2bf(float x) {
    __hip_bfloat16 h = __float2bfloat16(x);
    return *reinterpret_cast<unsigned short*>(&h);
}
__device__ __forceinline__ float bf2f(unsigned short u) {
    union { unsigned int i; float f; } c; c.i = ((unsigned int)u) << 16; return c.f;
}
__device__ __forceinline__ float bflo(unsigned int u) {
    union { unsigned int i; float f; } c; c.i = u << 16; return c.f;
}
__device__ __forceinline__ float bfhi(unsigned int u) {
    union { unsigned int i; float f; } c; c.i = u & 0xffff0000u; return c.f;
}

// async global->LDS, 16B per lane; LDS dest = wave-uniform base + lane*16B
__device__ __forceinline__ void gload_lds16(const void* g, void* l) {
    __builtin_amdgcn_global_load_lds(
        (const __attribute__((address_space(1))) unsigned int*)g,
        (__attribute__((address_space(3))) unsigned int*)l, 16, 0, 0);
}

#define TM 128
#define TN 256
#define TBK 32
#define EBS 264   // epilogue LDS row stride in ushorts (528 B, 16B-aligned)

// ---------------------------------------------------------------------------
// GEMM core, occupancy-oriented (R6): 512 threads, 8 waves 2x4, per-wave
// output 64x64 -> acc[4][4] = 64 VGPRs (vs 128 before).  Target: <=128
// VGPR/wave -> 4 waves/SIMD -> 2048 resident threads/CU (4x the 2-blocks-
// of-256 structure).  Wave-level overlap across blocks hides the per-K-step
// barrier vmcnt drain (m114 mechanism) -- in-kernel dbuf was proven neutral.
// Single-buffered 24KB LDS, 3 gload_lds16 per thread per K-step.
// ---------------------------------------------------------------------------
__device__ __forceinline__ void gemm_core(
    const unsigned short* __restrict__ A,
    const unsigned short* __restrict__ Bt,
    unsigned short* smem,
    int bm, int bn, int N, int K,
    int tid, int lane, int wm, int wn,
    f32x4 acc[4][4])
{
    const int sr = tid >> 6;            // wave id 0..7
    const int fr = lane & 15;
    const int fk = (lane >> 4) * 8;

    const unsigned short* aR  = A  + (size_t)(bm + sr * 16 + fr) * K + fk;
    const unsigned short* bR0 = Bt + (size_t)min(bn + sr * 16 + fr,       N - 1) * K + fk;
    const unsigned short* bR1 = Bt + (size_t)min(bn + (sr + 8) * 16 + fr, N - 1) * K + fk;

    unsigned short* sA = smem;                 // [8 stripes][512]
    unsigned short* sB = smem + TM * TBK;      // [16 stripes][512]

    for (int k0 = 0; k0 < K; k0 += TBK) {
        gload_lds16(aR  + k0, &sA[sr * 512]);
        gload_lds16(bR0 + k0, &sB[sr * 512]);
        gload_lds16(bR1 + k0, &sB[(sr + 8) * 512]);
        __syncthreads();

        short8 af[4], bfr[4];
        #pragma unroll
        for (int i = 0; i < 4; ++i)
            af[i] = *(const short8*)&sA[(wm * 4 + i) * 512 + lane * 8];
        #pragma unroll
        for (int j = 0; j < 4; ++j)
            bfr[j] = *(const short8*)&sB[(wn * 4 + j) * 512 + lane * 8];
        #pragma unroll
        for (int i = 0; i < 4; ++i)
            #pragma unroll
            for (int j = 0; j < 4; ++j)
                acc[i][j] = __builtin_amdgcn_mfma_f32_16x16x32_bf16(
                    af[i], bfr[j], acc[i][j], 0, 0, 0);
        __syncthreads();
    }
}

// ---------------------------------------------------------------------------
// Plain GEMM (ffn1): C row-major bf16, optional relu.  512 threads.
// ---------------------------------------------------------------------------
__global__ __launch_bounds__(512, 4) void gemm_mfma(
    const unsigned short* __restrict__ A,
    const unsigned short* __restrict__ Bt, const float* __restrict__ bias,
    unsigned short* __restrict__ Cb,
    int M, int N, int K, int relu)
{
    __shared__ __align__(16) unsigned short smem[TM * TBK + TN * TBK];
    const int tid  = threadIdx.x;
    const int lane = tid & 63;
    const int wave = tid >> 6;
    const int wm = wave >> 2, wn = wave & 3;
    const int bm = blockIdx.y * TM;
    const int bn = blockIdx.x * TN;

    f32x4 acc[4][4];
    #pragma unroll
    for (int i = 0; i < 4; ++i)
        #pragma unroll
        for (int j = 0; j < 4; ++j)
            acc[i][j] = (f32x4){0.f, 0.f, 0.f, 0.f};

    gemm_core(A, Bt, smem, bm, bn, N, K, tid, lane, wm, wn, acc);

    const int r0 = (lane >> 4) * 4;
    const int c0 = lane & 15;
    unsigned short* eb = smem;
    #pragma unroll
    for (int i = 0; i < 4; ++i) {
        if (i) __syncthreads();
        #pragma unroll
        for (int j = 0; j < 4; ++j) {
            const int col = bn + wn * 64 + j * 16 + c0;
            const float bj = (col < N) ? bias[col] : 0.f;
            #pragma unroll
            for (int r = 0; r < 4; ++r) {
                float v = acc[i][j][r] + bj;
                if (relu) v = fmaxf(v, 0.f);
                eb[(wm * 16 + r0 + r) * EBS + wn * 64 + j * 16 + c0] = f2bf(v);
            }
        }
        __syncthreads();
        #pragma unroll
        for (int qq = 0; qq < 2; ++qq) {
            const int q  = tid + qq * 512;
            const int rl = q >> 5;
            const int ch = q & 31;
            const int grow = bm + (rl >> 4) * 64 + i * 16 + (rl & 15);
            const int colb = bn + ch * 8;
            if (colb < N)
                *(uint4*)&Cb[(size_t)grow * N + colb] =
                    *(const uint4*)&eb[rl * EBS + ch * 8];
        }
    }
}

// ---------------------------------------------------------------------------
// Fused projection dispatch: bx=0 -> value (masked, head-major vT out);
// bx=1,2 -> qproj (N=384, row-major out). One launch, 3*(NTOK/TM) blocks.
// ---------------------------------------------------------------------------
__global__ __launch_bounds__(512, 4) void gemm_proj(
    const unsigned short* __restrict__ A0, const unsigned short* __restrict__ B0,
    const float* __restrict__ bias0, unsigned short* __restrict__ C0,
    const unsigned char* __restrict__ mask,
    const unsigned short* __restrict__ A1, const unsigned short* __restrict__ B1,
    const float* __restrict__ bias1, unsigned short* __restrict__ C1)
{
    __shared__ __align__(16) unsigned short smem[TM * TBK + TN * TBK];
    const int tid  = threadIdx.x;
    const int lane = tid & 63;
    const int wave = tid >> 6;
    const int wm = wave >> 2, wn = wave & 3;
    const int bm = blockIdx.y * TM;
    const int bx = blockIdx.x;

    const int isv = (bx == 0);
    const unsigned short* A    = isv ? A0 : A1;
    const unsigned short* Bt   = isv ? B0 : B1;
    const float*          bias = isv ? bias0 : bias1;
    const int N  = isv ? 256 : 384;
    const int bn = isv ? 0 : (bx - 1) * 256;
    const int K  = 256;

    f32x4 acc[4][4];
    #pragma unroll
    for (int i = 0; i < 4; ++i)
        #pragma unroll
        for (int j = 0; j < 4; ++j)
            acc[i][j] = (f32x4){0.f, 0.f, 0.f, 0.f};

    gemm_core(A, Bt, smem, bm, bn, N, K, tid, lane, wm, wn, acc);

    const int r0 = (lane >> 4) * 4;
    const int c0 = lane & 15;
    unsigned short* eb = smem;
    #pragma unroll
    for (int i = 0; i < 4; ++i) {
        if (i) __syncthreads();
        #pragma unroll
        for (int j = 0; j < 4; ++j) {
            const int col = bn + wn * 64 + j * 16 + c0;
            const float bj = (col < N) ? bias[col] : 0.f;
            #pragma unroll
            for (int r = 0; r < 4; ++r) {
                const int row = bm + wm * 64 + i * 16 + r0 + r;
                float v = acc[i][j][r] + bj;
                if (isv && mask[row]) v = 0.f;
                eb[(wm * 16 + r0 + r) * EBS + wn * 64 + j * 16 + c0] = f2bf(v);
            }
        }
        __syncthreads();
        #pragma unroll
        for (int qq = 0; qq < 2; ++qq) {
            const int q  = tid + qq * 512;
            const int rl = q >> 5;
            const int ch = q & 31;
            const int grow = bm + (rl >> 4) * 64 + i * 16 + (rl & 15);
            const int colb = bn + ch * 8;
            if (colb < N) {
                const uint4 val = *(const uint4*)&eb[rl * EBS + ch * 8];
                if (isv) {
                    const int bb   = grow >= LTOK;
                    const int srow = grow - bb * LTOK;
                    const int hcol = ch >> 2;
                    const int d    = (ch & 3) * 8;
                    *(uint4*)&C0[((size_t)(bb * 8 + hcol) * LTOK + srow) * 32 + d] = val;
                } else {
                    *(uint4*)&C1[(size_t)grow * 384 + colb] = val;
                }
            }
        }
    }
}

// ---------------------------------------------------------------------------
// GEMM + LayerNorm fusion (N=256):  y = LN(resid + A@Bt^T + bias) * g + be
// 512 threads; LN phase: 16 lanes/row over 32-row slabs, shfl width 16.
// ---------------------------------------------------------------------------
__global__ __launch_bounds__(512, 4) void gemm_ln(
    const unsigned short* __restrict__ A,
    const unsigned short* __restrict__ Bt, const float* __restrict__ bias,
    const unsigned short* __restrict__ resid,
    const float* __restrict__ g, const float* __restrict__ be,
    float* __restrict__ outF, unsigned short* __restrict__ outB, int K)
{
    __shared__ __align__(16) unsigned short smem[TM * TBK + TN * TBK];
    const int tid  = threadIdx.x;
    const int lane = tid & 63;
    const int wave = tid >> 6;
    const int wm = wave >> 2, wn = wave & 3;
    const int bm = blockIdx.y * TM;

    f32x4 acc[4][4];
    #pragma unroll
    for (int i = 0; i < 4; ++i)
        #pragma unroll
        for (int j = 0; j < 4; ++j)
            acc[i][j] = (f32x4){0.f, 0.f, 0.f, 0.f};

    gemm_core(A, Bt, smem, bm, 0, 256, K, tid, lane, wm, wn, acc);

    const int r0 = (lane >> 4) * 4;
    const int c0 = lane & 15;
    unsigned short* eb = smem;

    #pragma unroll
    for (int i = 0; i < 4; ++i) {
        if (i) __syncthreads();
        // stage slab (gemm result + bias) as bf16
        #pragma unroll
        for (int j = 0; j < 4; ++j) {
            const int col = wn * 64 + j * 16 + c0;
            const float bj = bias[col];
            #pragma unroll
            for (int r = 0; r < 4; ++r)
                eb[(wm * 16 + r0 + r) * EBS + col] = f2bf(acc[i][j][r] + bj);
        }
        __syncthreads();

        // LN over the 32 staged rows: 16 lanes/row, 16 cols each
        const int row = tid >> 4;            // 0..31
        const int l   = tid & 15;            // lane within row
        const int grow = bm + (row >> 4) * 64 + i * 16 + (row & 15);
        const unsigned short* rr = resid + (size_t)grow * 256 + l * 16;

        float s = 0.f, sq = 0.f;
        #pragma unroll
        for (int k = 0; k < 2; ++k) {
            const uint4 e = *(const uint4*)&eb[row * EBS + l * 16 + k * 8];
            const uint4 rv = *(const uint4*)(rr + k * 8);
            const unsigned int eu[4] = {e.x, e.y, e.z, e.w};
            const unsigned int ru[4] = {rv.x, rv.y, rv.z, rv.w};
            #pragma unroll
            for (int q = 0; q < 4; ++q) {
                const float v0 = bflo(eu[q]) + bflo(ru[q]);
                const float v1 = bfhi(eu[q]) + bfhi(ru[q]);
                s += v0 + v1;
                sq += v0 * v0 + v1 * v1;
            }
        }
        #pragma unroll
        for (int m = 8; m; m >>= 1) {
            s  += __shfl_xor(s, m, 16);
            sq += __shfl_xor(sq, m, 16);
        }
        const float mean = s * (1.f / 256.f);
        const float var  = sq * (1.f / 256.f) - mean * mean;
        const float rs   = rsqrtf(var + 1e-5f);

        #pragma unroll
        for (int k = 0; k < 2; ++k) {
            const int col = l * 16 + k * 8;
            const uint4 e = *(const uint4*)&eb[row * EBS + col];
            const uint4 rv = *(const uint4*)(rr + k * 8);
            const unsigned int eu[4] = {e.x, e.y, e.z, e.w};
            const unsigned int ru[4] = {rv.x, rv.y, rv.z, rv.w};
            float o[8];
            #pragma unroll
            for (int q = 0; q < 4; ++q) {
                const float g0 = g[col + q * 2],     b0 = be[col + q * 2];
                const float g1 = g[col + q * 2 + 1], b1 = be[col + q * 2 + 1];
                o[q * 2]     = (bflo(eu[q]) + bflo(ru[q]) - mean) * rs * g0 + b0;
                o[q * 2 + 1] = (bfhi(eu[q]) + bfhi(ru[q]) - mean) * rs * g1 + b1;
            }
            if (outB) {
                uint4 pk;
                pk.x = (unsigned)f2bf(o[0]) | ((unsigned)f2bf(o[1]) << 16);
                pk.y = (unsigned)f2bf(o[2]) | ((unsigned)f2bf(o[3]) << 16);
                pk.z = (unsigned)f2bf(o[4]) | ((unsigned)f2bf(o[5]) << 16);
                pk.w = (unsigned)f2bf(o[6]) | ((unsigned)f2bf(o[7]) << 16);
                *(uint4*)(outB + (size_t)grow * 256 + col) = pk;
            } else {
                float4 f0 = make_float4(o[0], o[1], o[2], o[3]);
                float4 f1 = make_float4(o[4], o[5], o[6], o[7]);
                *(float4*)(outF + (size_t)grow * 256 + col) = f0;
                *(float4*)(outF + (size_t)grow * 256 + col + 4) = f1;
            }
        }
        __syncthreads();   // eb reads done before next slab staging
    }
}

// ---------------------------------------------------------------------------
// Prepass: sb = bf16(src), qs = bf16(src + pos). Vectorized x4.
// ---------------------------------------------------------------------------
__global__ __launch_bounds__(256) void prepass(
    const float* __restrict__ src, const float* __restrict__ pos,
    unsigned short* __restrict__ sb, unsigned short* __restrict__ qs)
{
    const size_t i = ((size_t)blockIdx.x * 256 + threadIdx.x) * 4;
    const float4 s = *(const float4*)(src + i);
    const float4 p = *(const float4*)(pos + i);
    ushort4 us, uq;
    us.x = f2bf(s.x); us.y = f2bf(s.y); us.z = f2bf(s.z); us.w = f2bf(s.w);
    uq.x = f2bf(s.x + p.x); uq.y = f2bf(s.y + p.y);
    uq.z = f2bf(s.z + p.z); uq.w = f2bf(s.w + p.w);
    *(ushort4*)(sb + i) = us;
    *(ushort4*)(qs + i) = uq;
}

// ---------------------------------------------------------------------------
// All weight transposes (f32 [K][N] -> bf16 [N][K]) + bias concat, 1 dispatch.
// ---------------------------------------------------------------------------
__global__ void transpose_all(
    const float* __restrict__ w_val, const float* __restrict__ w_off,
    const float* __restrict__ w_att, const float* __restrict__ w_out,
    const float* __restrict__ w1,    const float* __restrict__ w2,
    const float* __restrict__ b_off, const float* __restrict__ b_att,
    unsigned short* __restrict__ wvalT, unsigned short* __restrict__ woaT,
    unsigned short* __restrict__ woutT, unsigned short* __restrict__ w1T,
    unsigned short* __restrict__ w2T,   float* __restrict__ bcat)
{
    const int blk = blockIdx.x;
    const int tx = threadIdx.x, ty = threadIdx.y;   // 32 x 8
    if (blk == 736) {
        const int t = ty * 32 + tx;
        bcat[t] = (t < 256) ? b_off[t] : b_att[t - 256];
        if (t + 256 < 384) bcat[t + 256] = b_att[t];
        return;
    }
    const float* W; unsigned short* Wt; int K, N, base;
    if      (blk < 64)  { W = w_val; Wt = wvalT;           K = 256;  N = 256;  base = 0;   }
    else if (blk < 128) { W = w_off; Wt = woaT;            K = 256;  N = 256;  base = 64;  }
    else if (blk < 160) { W = w_att; Wt = woaT + 256*256;  K = 256;  N = 128;  base = 128; }
    else if (blk < 224) { W = w_out; Wt = woutT;           K = 256;  N = 256;  base = 160; }
    else if (blk < 480) { W = w1;    Wt = w1T;             K = 256;  N = 1024; base = 224; }
    else                { W = w2;    Wt = w2T;             K = 1024; N = 256;  base = 480; }
    const int local = blk - base;
    const int kb = local % (K / 32);
    const int nb = local / (K / 32);
    const int k0 = kb * 32, n0 = nb * 32;

    __shared__ float t[32][33];
    #pragma unroll
    for (int i = 0; i < 32; i += 8)
        t[ty + i][tx] = W[(size_t)(k0 + ty + i) * N + n0 + tx];
    __syncthreads();
    #pragma unroll
    for (int i = 0; i < 32; i += 8)
        Wt[(size_t)(n0 + ty + i) * K + k0 + tx] = f2bf(t[tx][ty + i]);
}

// ---------------------------------------------------------------------------
// Fused softmax + bilinear sampling (immediate-offset LDS rows; R4 lesson:
// XOR swizzle broke offset-immediate addressing and serialized gathers).
// ---------------------------------------------------------------------------
__global__ __launch_bounds__(256) void sample_kernel(
    const unsigned short* __restrict__ vT, const unsigned short* __restrict__ qp,
    const float* __restrict__ ref,
    const int* __restrict__ sshapes, const int* __restrict__ lstart,
    unsigned short* __restrict__ samp)
{
    __shared__ __align__(16) int   s_o[256][4];
    __shared__ __align__(16) float s_w[256][4];

    const int blk   = blockIdx.x;
    const int plane = blk & 15;
    const int chunk = blk >> 4;
    const int b = plane >> 3;
    const int h = plane & 7;
    const int s0 = chunk * 16;
    const int t = threadIdx.x;

    {
        const int tl = t >> 4;
        const int p  = t & 15;
        const int l  = p >> 2;
        const int pp = p & 3;
        const int H = sshapes[2 * l], W = sshapes[2 * l + 1];
        const float Wf = (float)W, Hf = (float)H;
        const size_t tok = (size_t)(b * LTOK + s0 + tl);

        const float ox = bf2f(qp[tok * 384 + h * 32 + l * 8 + pp * 2 + 0]);
        const float oy = bf2f(qp[tok * 384 + h * 32 + l * 8 + pp * 2 + 1]);
        const float rx = ref[tok * 8 + l * 2 + 0];
        const float ry = ref[tok * 8 + l * 2 + 1];

        const float x = (rx + ox / Wf) * Wf - 0.5f;
        const float y = (ry + oy / Hf) * Hf - 0.5f;
        const float x0 = floorf(x), y0 = floorf(y);
        const float dx = x - x0, dy = y - y0;
        const int x0i = (int)x0, y0i = (int)y0;
        const int s = lstart[l];

        const float a = bf2f(qp[tok * 384 + 256 + h * 16 + p]);
        float mx = a;
        #pragma unroll
        for (int m = 8; m; m >>= 1) mx = fmaxf(mx, __shfl_xor(mx, m, 16));
        const float e = __expf(a - mx);
        float ssum = e;
        #pragma unroll
        for (int m = 8; m; m >>= 1) ssum += __shfl_xor(ssum, m, 16);
        const float prob = e / ssum;

        const float cw[4] = {(1.f - dx) * (1.f - dy), dx * (1.f - dy),
                             (1.f - dx) * dy,         dx * dy};
        const int cx[4] = {x0i, x0i + 1, x0i,     x0i + 1};
        const int cy[4] = {y0i, y0i,     y0i + 1, y0i + 1};
        int4   o4;
        float4 w4;
        #pragma unroll
        for (int c = 0; c < 4; ++c) {
            const bool valid = (cx[c] >= 0) & (cx[c] < W) & (cy[c] >= 0) & (cy[c] < H);
            const int xi = min(max(cx[c], 0), W - 1);
            const int yi = min(max(cy[c], 0), H - 1);
            ((int*)&o4)[c]   = (s + yi * W + xi) * 64;
            ((float*)&w4)[c] = valid ? cw[c] * prob : 0.f;
        }
        const int r = p * 16 + tl;
        *(int4*)&s_o[r][0]   = o4;
        *(float4*)&s_w[r][0] = w4;
    }
    __syncthreads();

    const int tl = t >> 4;
    const int dp = t & 15;
    const char* vp = (const char*)(vT + (size_t)plane * LTOK * 32) + dp * 4;
    float acc0 = 0.f, acc1 = 0.f;
    #pragma unroll
    for (int p = 0; p < 16; ++p) {
        const int r = p * 16 + tl;
        const int4   o4 = *(const int4*)&s_o[r][0];
        const float4 w4 = *(const float4*)&s_w[r][0];
        const unsigned int u0 = *(const unsigned int*)(vp + o4.x);
        const unsigned int u1 = *(const unsigned int*)(vp + o4.y);
        const unsigned int u2 = *(const unsigned int*)(vp + o4.z);
        const unsigned int u3 = *(const unsigned int*)(vp + o4.w);
        acc0 = fmaf(w4.x, bflo(u0), acc0); acc1 = fmaf(w4.x, bfhi(u0), acc1);
        acc0 = fmaf(w4.y, bflo(u1), acc0); acc1 = fmaf(w4.y, bfhi(u1), acc1);
        acc0 = fmaf(w4.z, bflo(u2), acc0); acc1 = fmaf(w4.z, bfhi(u2), acc1);
        acc0 = fmaf(w4.w, bflo(u3), acc0); acc1 = fmaf(w4.w, bfhi(u3), acc1);
    }
    const unsigned int o = (unsigned)f2bf(acc0) | ((unsigned)f2bf(acc1) << 16);
    *(unsigned int*)(samp + (size_t)(b * LTOK + s0 + tl) * 256 + h * 32 + dp * 2) = o;
}

// ---------------------------------------------------------------------------
extern "C" void kernel_launch(void* const* d_in, const int* in_sizes, int n_in,
                              void* d_out, int out_size, void* d_ws, size_t ws_size,
                              hipStream_t stream)
{
    const float* src   = (const float*)d_in[0];
    const float* pos   = (const float*)d_in[1];
    const float* ref   = (const float*)d_in[2];
    const int*   sshap = (const int*)d_in[3];
    const int*   lstrt = (const int*)d_in[4];
    const unsigned char* mask = (const unsigned char*)d_in[5];
    const float* w_off = (const float*)d_in[6];
    const float* b_off = (const float*)d_in[7];
    const float* w_att = (const float*)d_in[8];
    const float* b_att = (const float*)d_in[9];
    const float* w_val = (const float*)d_in[10];
    const float* b_val = (const float*)d_in[11];
    const float* w_out = (const float*)d_in[12];
    const float* b_out = (const float*)d_in[13];
    const float* ln1g  = (const float*)d_in[14];
    const float* ln1b  = (const float*)d_in[15];
    const float* w1    = (const float*)d_in[16];
    const float* b1    = (const float*)d_in[17];
    const float* w2    = (const float*)d_in[18];
    const float* b2    = (const float*)d_in[19];
    const float* ln2g  = (const float*)d_in[20];
    const float* ln2b  = (const float*)d_in[21];
    float* out = (float*)d_out;

    // ---- workspace (~146 MB), time-disjoint reuse ----
    const size_t HSZ = (size_t)NTOK * 256 * 2;    // 22.28 MB
    char* w = (char*)d_ws;
    unsigned short* qs     = (unsigned short*)w;
    unsigned short* samp16 = (unsigned short*)w;
    unsigned short* qpb    = (unsigned short*)(w + HSZ);
    unsigned short* vT     = (unsigned short*)(w + HSZ * 5 / 2);
    unsigned short* hidb   = (unsigned short*)w;                 // [NTOK][1024]
    unsigned short* sb     = (unsigned short*)(w + HSZ * 9 / 2);
    unsigned short* xb     = (unsigned short*)(w + HSZ * 11 / 2);
    char* wreg = w + HSZ * 13 / 2;
    unsigned short* wvalT  = (unsigned short*)wreg;
    unsigned short* woaT   = wvalT + 256 * 256;       // [384][256]
    unsigned short* woutT  = woaT + 384 * 256;
    unsigned short* w1T    = woutT + 256 * 256;
    unsigned short* w2T    = w1T + 1024 * 256;
    float*          bcat   = (float*)(w2T + 256 * 1024);

    const dim3 blk(256);
    const dim3 blk512(512);

    // 1. prepass: sb = bf16(src), qs = bf16(src+pos)
    prepass<<<dim3(NTOK / 4), blk, 0, stream>>>(src, pos, sb, qs);

    // 2. all weight transposes + bias concat
    transpose_all<<<dim3(737), dim3(32, 8), 0, stream>>>(
        w_val, w_off, w_att, w_out, w1, w2, b_off, b_att,
        wvalT, woaT, woutT, w1T, w2T, bcat);

    // 3. fused: value -> vT (head-major, masked) + qproj -> qpb.
    gemm_proj<<<dim3(3, NTOK / TM), blk512, 0, stream>>>(
        sb, wvalT, b_val, vT, mask, qs, woaT, bcat, qpb);

    // 4. softmax + bilinear sampling -> samp16 (qs dead)
    sample_kernel<<<dim3(16 * (LTOK / 16)), blk, 0, stream>>>(
        vT, qpb, ref, sshap, lstrt, samp16);

    // 5. xb = LN1(sb + samp @ w_out + b_out)  [fused gemm+LN]
    gemm_ln<<<dim3(1, NTOK / TM), blk512, 0, stream>>>(
        samp16, woutT, b_out, sb, ln1g, ln1b, nullptr, xb, 256);

    // 6. hidden = relu(xb @ w1 + b1) -> hidb (overlays dead regions)
    gemm_mfma<<<dim3(4, NTOK / TM), blk512, 0, stream>>>(
        xb, w1T, b1, hidb, NTOK, DFFN, 256, 1);

    // 7. out = LN2(xb + hidb @ w2 + b2)  [fused gemm+LN, f32 out]
    gemm_ln<<<dim3(1, NTOK / TM), blk512, 0, stream>>>(
        hidb, w2T, b2, xb, ln2g, ln2b, out, nullptr, DFFN);
}